// Round 6
// baseline (17540.471 us; speedup 1.0000x reference)
//
#include <hip/hip_runtime.h>
#include <math.h>

#define DI __device__ __forceinline__

// ---------------- dims ----------------
constexpr int TB = 16, TT = 64, NF = 1040, FSD = 1280;
constexpr int CHF = 208;   // encoder frame-chunk (5 chunks)
constexpr int CHN = 256;   // decoder sample-chunk (4 chunks)

// ---------------- ws layout (float offsets), total ~19.9M floats = 79.6 MB ----------------
// region R0: encoder chunk bufs, overlaid by decoder chunk bufs
constexpr size_t OFF_X1C  = 0;          // 208*32*1024 = 6,815,744
constexpr size_t OFF_X2C  = 6815744;    // 208*64*256  = 3,407,872
constexpr size_t OFF_X3C  = 10223616;   // 208*128*64  = 1,703,936 -> ends 11,927,552
constexpr size_t OFF_D0T  = 0;          // 1024*256 = 262,144
constexpr size_t OFF_DD1  = 262144;     // 3200*256 = 819,200
constexpr size_t OFF_DD2  = 1081344;    // 64*169*256 = 2,768,896
constexpr size_t OFF_DD3  = 3850240;    // 32*900*256 = 7,372,800 -> ends 11,223,040
// x4 region, overlaid by decoder weight transforms after enclin
constexpr size_t OFF_X4   = 11927552;   // 1040*256*16 = 4,259,840 -> ends 16,187,392
constexpr size_t OFF_W1T  = 11927552;   // 3,276,800
constexpr size_t OFF_W2T  = 15204352;   // 204,800
constexpr size_t OFF_W3T  = 15409152;   // 73,728
constexpr size_t OFF_W4P  = 15482880;   // 3,456 -> ends 15,486,336
// persistent
constexpr size_t OFF_EMB  = 16187392;   // 1040*256 = 266,240
constexpr size_t OFF_FULL = 16453632;   // 1024*1280 = 1,310,720
constexpr size_t OFF_PRI  = 17764352;   // 1,048,576
constexpr size_t OFF_POS  = 18812928;   // 1,048,576
constexpr size_t OFF_H    = 19861504;   // 4,096
constexpr size_t OFF_GI   = 19865600;   // 12,288
constexpr size_t OFF_GH   = 19877888;   // 12,288
constexpr size_t OFF_Q1   = 19890176;   // 4,096
constexpr size_t OFF_CIDX = 19894272;   // 512 ints
constexpr size_t OFF_BARS = 19894784;   // 512 ints
constexpr size_t OFF_ACC  = 19895296;   // 8 doubles (16 floats), byte off %8==0
constexpr size_t WS_NEED_BYTES = (OFF_ACC + 16) * 4;

// ================= init =================
__global__ void k_init(int* bars, double* accs) {
  int i = threadIdx.x;
  if (i < 512) bars[i] = 0;
  if (i < 4) accs[i] = 0.0;
}

// ================= encoder conv1: 3x64x64 -> 32x32x32 (chunk of CHF frames) =================
__global__ void __launch_bounds__(256) k_conv1(const float* __restrict__ obs,
    const float* __restrict__ w, const float* __restrict__ b, float* __restrict__ out, int fb) {
  __shared__ float in_s[3*66*66];
  __shared__ float w_s[32*48];
  const int f = blockIdx.x, tid = threadIdx.x;
  const float* src = obs + (size_t)(fb + f)*12288;
  for (int i = tid; i < 3*66*66; i += 256) {
    int c = i/4356, p = i%4356, y = p/66, x = p%66;
    float v = 0.f;
    if (y >= 1 && y <= 64 && x >= 1 && x <= 64) v = src[(c<<12) + ((y-1)<<6) + (x-1)];
    in_s[i] = v;
  }
  for (int i = tid; i < 32*48; i += 256) w_s[i] = w[i];
  __syncthreads();
  for (int pp = 0; pp < 4; ++pp) {
    int pos = tid + pp*256;
    int y = pos >> 5, x = pos & 31;
    float tp[48];
    #pragma unroll
    for (int c = 0; c < 3; ++c)
      #pragma unroll
      for (int ky = 0; ky < 4; ++ky)
        #pragma unroll
        for (int kx = 0; kx < 4; ++kx)
          tp[c*16+ky*4+kx] = in_s[c*4356 + (2*y+ky)*66 + (2*x+kx)];
    for (int o = 0; o < 32; ++o) {
      float acc = b[o];
      #pragma unroll
      for (int t = 0; t < 48; ++t) acc += tp[t]*w_s[o*48+t];
      out[((size_t)f*32 + o)*1024 + pos] = fmaxf(acc, 0.f);
    }
  }
}

// ================= conv2: 32x32x32 -> 64x16x16 (chunk-local) =================
__global__ void __launch_bounds__(256) k_conv2(const float* __restrict__ in,
    const float* __restrict__ w, const float* __restrict__ bias, float* __restrict__ out) {
  __shared__ float in_s[8*34*34];
  __shared__ float w_s[32*128];
  const int f = blockIdx.x, oh = blockIdx.y, tid = threadIdx.x;
  const int y = tid >> 4, x = tid & 15;
  float acc[32];
  #pragma unroll
  for (int o = 0; o < 32; ++o) acc[o] = bias[oh*32 + o];
  for (int cc = 0; cc < 4; ++cc) {
    __syncthreads();
    for (int i = tid; i < 8*34*34; i += 256) {
      int c = i/1156, p = i%1156, yy = p/34, xx = p%34;
      float v = 0.f;
      if (yy >= 1 && yy <= 32 && xx >= 1 && xx <= 32)
        v = in[((size_t)f*32 + cc*8 + c)*1024 + ((yy-1)<<5) + (xx-1)];
      in_s[i] = v;
    }
    for (int i = tid; i < 4096; i += 256) {
      int o = i >> 7, r = i & 127;
      w_s[i] = w[(oh*32+o)*512 + cc*128 + r];
    }
    __syncthreads();
    #pragma unroll
    for (int c = 0; c < 8; ++c) {
      float tp[16];
      #pragma unroll
      for (int ky = 0; ky < 4; ++ky)
        #pragma unroll
        for (int kx = 0; kx < 4; ++kx)
          tp[ky*4+kx] = in_s[c*1156 + (2*y+ky)*34 + (2*x+kx)];
      #pragma unroll
      for (int o = 0; o < 32; ++o) {
        float a2 = acc[o];
        #pragma unroll
        for (int t = 0; t < 16; ++t) a2 += tp[t]*w_s[(o<<7) + (c<<4) + t];
        acc[o] = a2;
      }
    }
  }
  #pragma unroll
  for (int o = 0; o < 32; ++o)
    out[((size_t)f*64 + oh*32 + o)*256 + tid] = fmaxf(acc[o], 0.f);
}

// ================= conv3: 64x16x16 -> 128x8x8 (chunk-local) =================
__global__ void __launch_bounds__(256) k_conv3(const float* __restrict__ in,
    const float* __restrict__ w, const float* __restrict__ bias, float* __restrict__ out) {
  __shared__ float in_s[4*18*18];
  __shared__ float w_s[128*64];
  const int f = blockIdx.x, tid = threadIdx.x;
  const int pos = tid & 63, cog = tid >> 6;
  const int y = pos >> 3, x = pos & 7;
  float acc[32];
  #pragma unroll
  for (int o = 0; o < 32; ++o) acc[o] = bias[cog*32+o];
  for (int cc = 0; cc < 16; ++cc) {
    __syncthreads();
    for (int i = tid; i < 1296; i += 256) {
      int c = i/324, p = i%324, yy = p/18, xx = p%18;
      float v = 0.f;
      if (yy >= 1 && yy <= 16 && xx >= 1 && xx <= 16)
        v = in[((size_t)f*64 + cc*4 + c)*256 + ((yy-1)<<4) + (xx-1)];
      in_s[i] = v;
    }
    for (int i = tid; i < 8192; i += 256) {
      int o = i >> 6, r = i & 63;
      w_s[i] = w[o*1024 + cc*64 + r];
    }
    __syncthreads();
    #pragma unroll
    for (int c = 0; c < 4; ++c) {
      float tp[16];
      #pragma unroll
      for (int ky = 0; ky < 4; ++ky)
        #pragma unroll
        for (int kx = 0; kx < 4; ++kx)
          tp[ky*4+kx] = in_s[c*324 + (2*y+ky)*18 + (2*x+kx)];
      #pragma unroll
      for (int o = 0; o < 32; ++o) {
        float a2 = acc[o];
        #pragma unroll
        for (int t = 0; t < 16; ++t) a2 += tp[t]*w_s[((cog*32+o)<<6) + (c<<4) + t];
        acc[o] = a2;
      }
    }
  }
  #pragma unroll
  for (int o = 0; o < 32; ++o)
    out[((size_t)f*128 + cog*32 + o)*64 + pos] = fmaxf(acc[o], 0.f);
}

// ================= conv4 (GEMM-ish): 128x8x8 -> 256x4x4 ; in chunk-local, out global =================
__global__ void __launch_bounds__(256) k_conv4(const float* __restrict__ in,
    const float* __restrict__ w, const float* __restrict__ bias, float* __restrict__ out, int fb) {
  __shared__ float a_s[32*256];
  __shared__ float w_s[64*32];
  const int f0 = blockIdx.x * 16, o0 = blockIdx.y * 64, tid = threadIdx.x;
  const int fl = tid >> 4, pos = tid & 15;
  float acc[64];
  #pragma unroll
  for (int o = 0; o < 64; ++o) acc[o] = 0.f;
  for (int K0 = 0; K0 < 2048; K0 += 32) {
    __syncthreads();
    for (int i = tid; i < 8192; i += 256) {
      int kk = i >> 8, row = i & 255;
      int K = K0 + kk, ci = K >> 4, tap = K & 15;
      int ff = f0 + (row >> 4), pp = row & 15;
      int yy = ((pp >> 2) << 1) + (tap >> 2) - 1;
      int xx = ((pp & 3) << 1) + (tap & 3) - 1;
      float v = 0.f;
      if (yy >= 0 && yy < 8 && xx >= 0 && xx < 8)
        v = in[((size_t)ff*128 + ci)*64 + yy*8 + xx];
      a_s[kk*256 + row] = v;
    }
    for (int i = tid; i < 2048; i += 256) {
      int o = i >> 5, kk = i & 31;
      w_s[i] = w[(o0 + o)*2048 + K0 + kk];
    }
    __syncthreads();
    #pragma unroll
    for (int kk = 0; kk < 32; ++kk) {
      float av = a_s[kk*256 + tid];
      #pragma unroll
      for (int o = 0; o < 64; ++o) acc[o] += av * w_s[o*32 + kk];
    }
  }
  for (int o = 0; o < 64; ++o)
    out[(((size_t)(fb + f0 + fl))*256 + o0+o)*16 + pos] = fmaxf(acc[o] + bias[o0+o], 0.f);
}

// ================= encoder linear: 1040x4096 @ 4096x256 (full) =================
__global__ void __launch_bounds__(256) k_enclin(const float* __restrict__ x4,
    const float* __restrict__ w, const float* __restrict__ b, float* __restrict__ emb) {
  __shared__ float a_s[4*1024];
  const int f0 = blockIdx.x*4, tid = threadIdx.x;
  float acc[4] = {0.f,0.f,0.f,0.f};
  for (int K0 = 0; K0 < 4096; K0 += 1024) {
    __syncthreads();
    for (int i = tid; i < 4096; i += 256) {
      int r = i >> 10, k = i & 1023;
      a_s[i] = x4[((size_t)(f0+r))*4096 + K0 + k];
    }
    __syncthreads();
    for (int k = 0; k < 1024; ++k) {
      float wv = w[(K0+k)*256 + tid];
      #pragma unroll
      for (int r = 0; r < 4; ++r) acc[r] += a_s[(r<<10) + k] * wv;
    }
  }
  #pragma unroll
  for (int r = 0; r < 4; ++r) emb[((size_t)(f0+r))*256 + tid] = acc[r] + b[tid];
}

// ================= decoder weight transforms =================
__global__ void k_wtrans(const float* __restrict__ dw1, const float* __restrict__ dw2,
                         const float* __restrict__ dw3, const float* __restrict__ dw4,
                         float* __restrict__ w1t, float* __restrict__ w2t,
                         float* __restrict__ w3t, float* __restrict__ w4p) {
  int i = blockIdx.x*256 + threadIdx.x;
  if (i < 1024*3200) {    // w1t[k][o*25+y*5+x] = dw1[o][k][4-y][4-x]
    int k = i / 3200, c = i % 3200;
    int o = c / 25, r = c % 25, y = r / 5, x = r % 5;
    w1t[i] = dw1[(o*1024 + k)*25 + (4-y)*5 + (4-x)];
  }
  if (i < 25*128*64) {    // w2t[tap][i][o]  (tap unflipped: conv_transpose no-flip semantics)
    int tap = i / 8192, r = i % 8192, ii = r >> 6, o = r & 63;
    w2t[i] = dw2[(o*128 + ii)*25 + tap];
  }
  if (i < 36*64*32) {     // w3t[tap][i][o]
    int tap = i / 2048, r = i % 2048, ii = r >> 5, o = r & 31;
    w3t[i] = dw3[(o*64 + ii)*36 + tap];
  }
  if (i < 4*9*96) {       // w4p[par][d2*3+d][i*3+o],  ky=5-py-2*d2, kx=5-px-2*d
    int par = i / 864, r = i % 864, d9 = r / 96, q = r % 96, ii = q/3, o = q%3;
    int py = par >> 1, px = par & 1, d2 = d9 / 3, d = d9 % 3;
    int ky = 5 - py - 2*d2, kx = 5 - px - 2*d;
    w4p[i] = dw4[(o*32 + ii)*36 + ky*6 + kx];
  }
}

// ================= RSSM scan (regular launch, 256 co-resident blocks) =================
struct ScanArgs {
  const float *pre_w, *pre_b, *wi, *wh, *bi, *bh, *qw1, *qb1, *qw2, *qb2, *emb, *gum;
  const int* act;
  float *hbuf, *gibuf, *ghbuf, *q1buf, *fulls, *posts;
  int *curidx, *bars;
};

DI void chain_bar(int* bar, int target) {
  __syncthreads();
  if (threadIdx.x == 0) {
    __threadfence();
    __hip_atomic_fetch_add(bar, 1, __ATOMIC_RELEASE, __HIP_MEMORY_SCOPE_AGENT);
    while (__hip_atomic_load(bar, __ATOMIC_ACQUIRE, __HIP_MEMORY_SCOPE_AGENT) < target) {
      __builtin_amdgcn_s_sleep(1);
    }
  }
  __syncthreads();
  __threadfence();
}

__global__ void __launch_bounds__(256) k_scan(ScanArgs a) {
  const int tid = threadIdx.x;
  const int chain = blockIdx.x & 15;   // batch b (chain's 16 blocks share XCD: bid%8 = chain%8)
  const int sub = blockIdx.x >> 4;     // 0..15
  __shared__ float xin_s[256], h_s[256], h2_s[256], e_s[256], q1_s[256], red_s[256];
  __shared__ float post_s[64];
  __shared__ int idx_s[2];
  int* bar = a.bars + chain*32;
  int bk = 0;
  float* hb  = a.hbuf  + chain*256;
  float* gib = a.gibuf + chain*768;
  float* ghb = a.ghbuf + chain*768;
  float* q1b = a.q1buf + chain*256;
  int* cidx  = a.curidx + chain*32;

  for (int t = 0; t < TT; ++t) {
    const int row = chain*TT + t;
    // ---------- S1: xin (redundant per block) ; gi/gh slices ----------
    h_s[tid] = (t == 0) ? 0.f : hb[tid];
    {
      float v = a.pre_b[tid];
      int act = a.act[chain*TT + t];
      v += a.pre_w[(1024 + act)*256 + tid];
      if (t > 0) {
        #pragma unroll
        for (int c = 0; c < 32; ++c) {
          int ix = cidx[c];
          v += a.pre_w[(c*32 + ix)*256 + tid];
        }
      }
      xin_s[tid] = fmaxf(v, 0.f);
    }
    __syncthreads();
    if (tid < 192) {
      int cl = tid % 96, kp = tid / 96;
      int col = (sub & 7)*96 + cl;
      const float* W   = (sub < 8) ? a.wi : a.wh;
      const float* src = (sub < 8) ? xin_s : h_s;
      const float* wp = W + (size_t)(kp*128)*768 + col;
      const float* sp = src + kp*128;
      float p = 0.f;
      #pragma unroll 8
      for (int k = 0; k < 128; ++k) p += sp[k] * wp[(size_t)k*768];
      red_s[kp*96 + cl] = p;
    }
    __syncthreads();
    if (tid < 96) {
      int col = (sub & 7)*96 + tid;
      float v = red_s[tid] + red_s[96+tid];
      if (sub < 8) gib[col] = v + a.bi[col];
      else         ghb[col] = v + a.bh[col];
    }
    chain_bar(bar, 16*(++bk));
    // ---------- S2: gates (redundant) ; q1 slices ----------
    {
      float gi0 = gib[tid], gi1 = gib[256+tid], gi2 = gib[512+tid];
      float gh0 = ghb[tid], gh1 = ghb[256+tid], gh2 = ghb[512+tid];
      float r = 1.f/(1.f+expf(-(gi0+gh0)));
      float z = 1.f/(1.f+expf(-(gi1+gh1)));
      float nn = tanhf(gi2 + r*gh2);
      float hn = (1.f - z)*nn + z*h_s[tid];
      h2_s[tid] = hn;
      e_s[tid] = a.emb[((size_t)chain*65 + t + 1)*256 + tid];
      if (sub == 0) {
        hb[tid] = hn;
        a.fulls[(size_t)row*FSD + tid] = hn;
      }
    }
    __syncthreads();
    {
      int cl = tid & 15, kp = tid >> 4;
      int col = sub*16 + cl;
      float p = 0.f;
      int k0 = kp*32;
      #pragma unroll 8
      for (int k = 0; k < 32; ++k) {
        int kk = k0 + k;
        float v = (kk < 256) ? h2_s[kk] : e_s[kk-256];
        p += v * a.qw1[(size_t)kk*256 + col];
      }
      red_s[kp*16 + cl] = p;
    }
    __syncthreads();
    if (tid < 16) {
      int col = sub*16 + tid;
      float v = a.qb1[col];
      #pragma unroll
      for (int p = 0; p < 16; ++p) v += red_s[p*16 + tid];
      q1b[col] = fmaxf(v, 0.f);
    }
    chain_bar(bar, 16*(++bk));
    // ---------- S3: post slices ; argmax ; stoch ----------
    q1_s[tid] = q1b[tid];
    __syncthreads();
    {
      int cl = tid & 63, kp = tid >> 6;
      int col = sub*64 + cl;
      float p = 0.f;
      int k0 = kp*64;
      #pragma unroll 8
      for (int k = 0; k < 64; ++k) p += q1_s[k0+k] * a.qw2[(size_t)(k0+k)*1024 + col];
      red_s[kp*64 + cl] = p;
    }
    __syncthreads();
    if (tid < 64) {
      int col = sub*64 + tid;
      float v = a.qb2[col] + red_s[tid] + red_s[64+tid] + red_s[128+tid] + red_s[192+tid];
      a.posts[(size_t)row*1024 + col] = v;
      post_s[tid] = v;
    }
    __syncthreads();
    if (tid < 2) {
      int cat = sub*2 + tid;
      const float* g = a.gum + (((size_t)t*16 + chain)*32 + cat)*32;
      float best = post_s[tid*32] + g[0]; int bst = 0;
      #pragma unroll
      for (int k = 1; k < 32; ++k) {
        float v = post_s[tid*32 + k] + g[k];
        if (v > best) { best = v; bst = k; }
      }
      idx_s[tid] = bst;
      cidx[cat] = bst;
    }
    __syncthreads();
    if (tid < 64) {
      int k = tid & 31, cl = tid >> 5;
      a.fulls[(size_t)row*FSD + 256 + (sub*2 + cl)*32 + k] = (k == idx_s[cl]) ? 1.f : 0.f;
    }
    chain_bar(bar, 16*(++bk));
  }
}

// ================= priors (batched, post-scan) =================
__global__ void __launch_bounds__(256) k_priors(const float* __restrict__ fulls,
    const float* __restrict__ w1, const float* __restrict__ b1,
    const float* __restrict__ w2, const float* __restrict__ b2, float* __restrict__ priors) {
  __shared__ float h_s[16*256];
  __shared__ float p1_s[16*256];
  const int r0 = blockIdx.x*16, tid = threadIdx.x;
  for (int i = tid; i < 4096; i += 256) {
    int r = i >> 8, k = i & 255;
    h_s[i] = fulls[((size_t)(r0+r))*FSD + k];
  }
  __syncthreads();
  float acc[16];
  #pragma unroll
  for (int r = 0; r < 16; ++r) acc[r] = b1[tid];
  for (int k = 0; k < 256; ++k) {
    float wv = w1[k*256 + tid];
    #pragma unroll
    for (int r = 0; r < 16; ++r) acc[r] += h_s[(r<<8)+k]*wv;
  }
  #pragma unroll
  for (int r = 0; r < 16; ++r) p1_s[(r<<8)+tid] = fmaxf(acc[r], 0.f);
  __syncthreads();
  float a2[16][4];
  #pragma unroll
  for (int r = 0; r < 16; ++r)
    #pragma unroll
    for (int q = 0; q < 4; ++q) a2[r][q] = b2[q*256 + tid];
  for (int k = 0; k < 256; ++k) {
    float w0 = w2[k*1024 + tid], wv1 = w2[k*1024 + 256 + tid];
    float wv2 = w2[k*1024 + 512 + tid], wv3 = w2[k*1024 + 768 + tid];
    #pragma unroll
    for (int r = 0; r < 16; ++r) {
      float pv = p1_s[(r<<8)+k];
      a2[r][0] += pv*w0; a2[r][1] += pv*wv1; a2[r][2] += pv*wv2; a2[r][3] += pv*wv3;
    }
  }
  for (int r = 0; r < 16; ++r)
    #pragma unroll
    for (int q = 0; q < 4; ++q)
      priors[((size_t)(r0+r))*1024 + q*256 + tid] = a2[r][q];
}

// ================= decoder linear (chunk of CHN samples) -> d0t_c[k][n_local] =================
__global__ void __launch_bounds__(256) k_declin(const float* __restrict__ fulls,
    const float* __restrict__ w, const float* __restrict__ b, float* __restrict__ d0t, int nb) {
  __shared__ float f_s[32*257];
  __shared__ float w_s[32*32];
  const int k0 = blockIdx.x*32, tid = threadIdx.x;
  float acc[32];
  #pragma unroll
  for (int kt = 0; kt < 32; ++kt) acc[kt] = 0.f;
  for (int K0 = 0; K0 < 1280; K0 += 32) {
    __syncthreads();
    {
      const float4* src = (const float4*)(fulls + ((size_t)(nb+tid))*FSD + K0);
      #pragma unroll
      for (int q = 0; q < 8; ++q) {
        float4 v = src[q];
        f_s[(q*4+0)*257 + tid] = v.x;
        f_s[(q*4+1)*257 + tid] = v.y;
        f_s[(q*4+2)*257 + tid] = v.z;
        f_s[(q*4+3)*257 + tid] = v.w;
      }
    }
    for (int i = tid; i < 1024; i += 256) {
      int kk = i >> 5, kt = i & 31;
      w_s[i] = w[(size_t)(K0+kk)*1024 + k0 + kt];
    }
    __syncthreads();
    #pragma unroll
    for (int kk = 0; kk < 32; ++kk) {
      float hv = f_s[kk*257 + tid];
      #pragma unroll
      for (int kt = 0; kt < 32; ++kt) acc[kt] += hv * w_s[kk*32 + kt];
    }
  }
  for (int kt = 0; kt < 32; ++kt) d0t[((size_t)(k0+kt))*CHN + tid] = acc[kt] + b[k0+kt];
}

// ================= ct1: GEMM 1024K x 3200 cols (chunk-local n) =================
__global__ void __launch_bounds__(256) k_ct1(const float* __restrict__ d0t,
    const float* __restrict__ w1t, const float* __restrict__ db1, float* __restrict__ dd1) {
  __shared__ float w_s[32*32];
  const int c0 = blockIdx.x*32, tid = threadIdx.x;
  float acc[32];
  #pragma unroll
  for (int ct = 0; ct < 32; ++ct) acc[ct] = 0.f;
  for (int K0 = 0; K0 < 1024; K0 += 32) {
    __syncthreads();
    for (int i = tid; i < 1024; i += 256) {
      int kk = i >> 5, ct = i & 31;
      w_s[i] = w1t[(size_t)(K0+kk)*3200 + c0 + ct];
    }
    __syncthreads();
    #pragma unroll
    for (int kk = 0; kk < 32; ++kk) {
      float av = d0t[((size_t)(K0+kk))*CHN + tid];
      #pragma unroll
      for (int ct = 0; ct < 32; ++ct) acc[ct] += av * w_s[kk*32 + ct];
    }
  }
  #pragma unroll
  for (int ct = 0; ct < 32; ++ct)
    dd1[((size_t)(c0+ct))*CHN + tid] = fmaxf(acc[ct] + db1[(c0+ct)/25], 0.f);
}

// ================= ct2: 128x5x5 -> 64x13x13 (chunk-local n; o split by tid>>7) =================
__global__ void __launch_bounds__(256) k_ct2(const float* __restrict__ dd1,
    const float* __restrict__ w2t, const float* __restrict__ db2, float* __restrict__ dd2) {
  __shared__ float w_s[128*32];
  const int pos = blockIdx.x, og = blockIdx.y, tid = threadIdx.x;
  const int y = pos/13, x = pos%13;
  const int nl2 = (tid & 127)*2, oh = tid >> 7;   // oh in {0,1}: 16 o's each
  float acc[16][2];
  #pragma unroll
  for (int o = 0; o < 16; ++o) { acc[o][0] = 0.f; acc[o][1] = 0.f; }
  for (int ky = 0; ky < 5; ++ky) {
    int ty = y + ky - 4;
    if (ty & 1) continue;
    int iy = ty >> 1;
    if (iy < 0 || iy >= 5) continue;
    for (int kx = 0; kx < 5; ++kx) {
      int tx = x + kx - 4;
      if (tx & 1) continue;
      int ix = tx >> 1;
      if (ix < 0 || ix >= 5) continue;
      int tap = ky*5 + kx;
      __syncthreads();
      for (int i = tid; i < 4096; i += 256)
        w_s[i] = w2t[(size_t)tap*8192 + (i >> 5)*64 + og*32 + (i & 31)];
      __syncthreads();
      #pragma unroll 4
      for (int i = 0; i < 128; ++i) {
        float2 v = *(const float2*)(dd1 + ((size_t)(i*25 + iy*5 + ix))*CHN + nl2);
        #pragma unroll
        for (int o = 0; o < 16; ++o) {
          float wv = w_s[i*32 + oh*16 + o];
          acc[o][0] += v.x*wv; acc[o][1] += v.y*wv;
        }
      }
    }
  }
  for (int o = 0; o < 16; ++o) {
    int oo = og*32 + oh*16 + o;
    float bb = db2[oo];
    float2 r; r.x = fmaxf(acc[o][0]+bb, 0.f); r.y = fmaxf(acc[o][1]+bb, 0.f);
    *(float2*)(dd2 + ((size_t)(oo*169 + pos))*CHN + nl2) = r;
  }
}

// ================= ct3: 64x13x13 -> 32x30x30 (chunk-local n; o split) =================
__global__ void __launch_bounds__(256) k_ct3(const float* __restrict__ dd2,
    const float* __restrict__ w3t, const float* __restrict__ db3, float* __restrict__ dd3) {
  __shared__ float w_s[64*32];
  const int pos = blockIdx.x, tid = threadIdx.x;
  const int y = pos/30, x = pos%30;
  const int nl2 = (tid & 127)*2, oh = tid >> 7;
  float acc[16][2];
  #pragma unroll
  for (int o = 0; o < 16; ++o) { acc[o][0] = 0.f; acc[o][1] = 0.f; }
  for (int ky = 0; ky < 6; ++ky) {
    int ty = y + ky - 5;
    if (ty & 1) continue;
    int iy = ty >> 1;
    if (iy < 0 || iy >= 13) continue;
    for (int kx = 0; kx < 6; ++kx) {
      int tx = x + kx - 5;
      if (tx & 1) continue;
      int ix = tx >> 1;
      if (ix < 0 || ix >= 13) continue;
      int tap = ky*6 + kx;
      __syncthreads();
      for (int i = tid; i < 2048; i += 256) w_s[i] = w3t[(size_t)tap*2048 + i];
      __syncthreads();
      #pragma unroll 2
      for (int i = 0; i < 64; ++i) {
        float2 v = *(const float2*)(dd2 + ((size_t)(i*169 + iy*13 + ix))*CHN + nl2);
        #pragma unroll
        for (int o = 0; o < 16; ++o) {
          float wv = w_s[i*32 + oh*16 + o];
          acc[o][0] += v.x*wv; acc[o][1] += v.y*wv;
        }
      }
    }
  }
  for (int o = 0; o < 16; ++o) {
    int oo = oh*16 + o;
    float bb = db3[oo];
    float2 r; r.x = fmaxf(acc[o][0]+bb, 0.f); r.y = fmaxf(acc[o][1]+bb, 0.f);
    *(float2*)(dd3 + ((size_t)(oo*900 + pos))*CHN + nl2) = r;
  }
}

// ====== ct4 (32x30x30 -> 3x64x64) fused with recon MSE; parity-decomposed; chunk n ======
__global__ void __launch_bounds__(512) k_ct4loss(const float* __restrict__ dd3,
    const float* __restrict__ w4p, const float* __restrict__ db4,
    const float* __restrict__ obs, double* __restrict__ accRec, int nb) {
  __shared__ float in_s[16*10*6*16];  // [i16][iy10][ix6][n16]
  __shared__ float redf[8];
  const int tid = threadIdx.x, bx = blockIdx.x;
  const int nbt = bx & 15, xt = (bx >> 4) & 7, yt = bx >> 7;  // 16 n-tiles, 8 x'-tiles(4), 4 y'-tiles(8)
  const int n0 = nbt*16, Y0 = yt*8, X0 = xt*4;
  const int nl = tid & 15, ppos = tid >> 4;
  const int yl = ppos >> 2, xl = ppos & 3;
  float acc[4][3];
  #pragma unroll
  for (int p = 0; p < 4; ++p) { acc[p][0]=db4[0]; acc[p][1]=db4[1]; acc[p][2]=db4[2]; }
  for (int ch = 0; ch < 2; ++ch) {
    __syncthreads();
    for (int i = tid; i < 15360; i += 512) {
      int n2 = i & 15, r = i >> 4;
      int ix = r % 6, r2 = r / 6, iy = r2 % 10, ii = r2 / 10;
      int gy = Y0 - 2 + iy, gx = X0 - 2 + ix;
      float v = 0.f;
      if (gy >= 0 && gy < 30 && gx >= 0 && gx < 30)
        v = dd3[((size_t)((ch*16 + ii)*900 + gy*30 + gx))*CHN + n0 + n2];
      in_s[i] = v;
    }
    __syncthreads();
    #pragma unroll
    for (int par = 0; par < 4; ++par) {
      #pragma unroll
      for (int d2 = 0; d2 < 3; ++d2) {
        int iy = yl + 2 - d2;
        #pragma unroll
        for (int d = 0; d < 3; ++d) {
          int ix = xl + 2 - d;
          const float* wp = w4p + (par*9 + d2*3 + d)*96 + ch*48;
          #pragma unroll 4
          for (int ii = 0; ii < 16; ++ii) {
            float v = in_s[((ii*10 + iy)*6 + ix)*16 + nl];
            acc[par][0] += v*wp[ii*3+0];
            acc[par][1] += v*wp[ii*3+1];
            acc[par][2] += v*wp[ii*3+2];
          }
        }
      }
    }
  }
  const int n = nb + n0 + nl, b = n >> 6, t = n & 63;
  float lsum = 0.f;
  #pragma unroll
  for (int par = 0; par < 4; ++par) {
    int py = par >> 1, px = par & 1;
    int yy = 2*(Y0 + yl) + py, xx = 2*(X0 + xl) + px;
    const float* ob = obs + (size_t)((b*65 + t + 1)*3)*4096 + yy*64 + xx;
    float d0v = acc[par][0] - ob[0];
    float d1v = acc[par][1] - ob[4096];
    float d2v = acc[par][2] - ob[8192];
    lsum += d0v*d0v + d1v*d1v + d2v*d2v;
  }
  #pragma unroll
  for (int off = 32; off > 0; off >>= 1) lsum += __shfl_down(lsum, off);
  if ((tid & 63) == 0) redf[tid >> 6] = lsum;
  __syncthreads();
  if (tid == 0) {
    float s = 0.f;
    for (int i = 0; i < 8; ++i) s += redf[i];
    atomicAdd(accRec, (double)s);
  }
}

// ================= reward head + MSE =================
__global__ void __launch_bounds__(256) k_reward(const float* __restrict__ fulls,
    const float* __restrict__ w1, const float* __restrict__ b1,
    const float* __restrict__ w2, const float* __restrict__ b2,
    const float* __restrict__ rew, double* __restrict__ accR) {
  __shared__ float f_s[8*1280];
  __shared__ float h_s[8*256];
  const int r0 = blockIdx.x*8, tid = threadIdx.x;
  for (int i = tid; i < 8*1280; i += 256) f_s[i] = fulls[(size_t)r0*FSD + i];
  __syncthreads();
  float acc[8];
  #pragma unroll
  for (int r = 0; r < 8; ++r) acc[r] = b1[tid];
  for (int k = 0; k < 1280; ++k) {
    float wv = w1[(size_t)k*256 + tid];
    #pragma unroll
    for (int r = 0; r < 8; ++r) acc[r] += f_s[r*1280 + k] * wv;
  }
  #pragma unroll
  for (int r = 0; r < 8; ++r) h_s[(r<<8) + tid] = fmaxf(acc[r], 0.f);
  __syncthreads();
  int r = tid >> 5, l = tid & 31;
  float p = 0.f;
  for (int j = l; j < 256; j += 32) p += h_s[(r<<8) + j] * w2[j];
  #pragma unroll
  for (int off = 16; off > 0; off >>= 1) p += __shfl_down(p, off, 32);
  if (l == 0) {
    float d = p + b2[0] - rew[r0 + r];
    atomicAdd(accR, (double)(d*d));
  }
}

// ================= KL =================
__global__ void __launch_bounds__(256) k_kl(const float* __restrict__ posts,
    const float* __restrict__ priors, double* __restrict__ accK) {
  const int u = blockIdx.x*256 + threadIdx.x;   // 0..32767 = row*32 + cat
  const float* po = posts  + (size_t)(u >> 5)*1024 + (u & 31)*32;
  const float* pr = priors + (size_t)(u >> 5)*1024 + (u & 31)*32;
  float pv[32], qv[32];
  float m1 = -1e30f, m2 = -1e30f;
  #pragma unroll
  for (int k = 0; k < 32; ++k) {
    pv[k] = po[k]; m1 = fmaxf(m1, pv[k]);
    qv[k] = pr[k]; m2 = fmaxf(m2, qv[k]);
  }
  float s1 = 0.f, s2 = 0.f;
  #pragma unroll
  for (int k = 0; k < 32; ++k) {
    pv[k] = expf(pv[k]-m1); s1 += pv[k];
    qv[k] = expf(qv[k]-m2); s2 += qv[k];
  }
  float i1 = 1.f/s1, i2 = 1.f/s2;
  float kl = 0.f;
  #pragma unroll
  for (int k = 0; k < 32; ++k) {
    float pp = pv[k]*i1 + 1e-8f;
    float qq = qv[k]*i2 + 1e-8f;
    kl += pp * (logf(pp) - logf(qq));
  }
  #pragma unroll
  for (int off = 32; off > 0; off >>= 1) kl += __shfl_down(kl, off);
  __shared__ float red[4];
  if ((threadIdx.x & 63) == 0) red[threadIdx.x >> 6] = kl;
  __syncthreads();
  if (threadIdx.x == 0) atomicAdd(accK, (double)(red[0]+red[1]+red[2]+red[3]));
}

// ================= finalize =================
__global__ void k_fin(const double* __restrict__ accs, float* __restrict__ out) {
  out[0] = (float)(accs[0]/12582912.0 + accs[1]/1024.0 + accs[2]/32768.0);
}

// ================= launcher =================
extern "C" void kernel_launch(void* const* d_in, const int* in_sizes, int n_in,
                              void* d_out, int out_size, void* d_ws, size_t ws_size,
                              hipStream_t stream) {
  (void)in_sizes; (void)n_in; (void)out_size;
  if (ws_size < WS_NEED_BYTES) return;   // undersized ws -> fail visibly, not fault
  const float* obs   = (const float*)d_in[0];
  const int*   act   = (const int*)  d_in[1];
  const float* rew   = (const float*)d_in[2];
  const float* ew1   = (const float*)d_in[3];
  const float* eb1   = (const float*)d_in[4];
  const float* ew2   = (const float*)d_in[5];
  const float* eb2   = (const float*)d_in[6];
  const float* ew3   = (const float*)d_in[7];
  const float* eb3   = (const float*)d_in[8];
  const float* ew4   = (const float*)d_in[9];
  const float* eb4   = (const float*)d_in[10];
  const float* enc_lw= (const float*)d_in[11];
  const float* enc_lb= (const float*)d_in[12];
  const float* pre_w = (const float*)d_in[13];
  const float* pre_b = (const float*)d_in[14];
  const float* gru_wi= (const float*)d_in[15];
  const float* gru_wh= (const float*)d_in[16];
  const float* gru_bi= (const float*)d_in[17];
  const float* gru_bh= (const float*)d_in[18];
  const float* pri_w1= (const float*)d_in[19];
  const float* pri_b1= (const float*)d_in[20];
  const float* pri_w2= (const float*)d_in[21];
  const float* pri_b2= (const float*)d_in[22];
  const float* post_w1=(const float*)d_in[23];
  const float* post_b1=(const float*)d_in[24];
  const float* post_w2=(const float*)d_in[25];
  const float* post_b2=(const float*)d_in[26];
  const float* dec_lw= (const float*)d_in[27];
  const float* dec_lb= (const float*)d_in[28];
  const float* dw1   = (const float*)d_in[29];
  const float* db1   = (const float*)d_in[30];
  const float* dw2   = (const float*)d_in[31];
  const float* db2   = (const float*)d_in[32];
  const float* dw3   = (const float*)d_in[33];
  const float* db3   = (const float*)d_in[34];
  const float* dw4   = (const float*)d_in[35];
  const float* db4   = (const float*)d_in[36];
  const float* rw1   = (const float*)d_in[37];
  const float* rb1   = (const float*)d_in[38];
  const float* rw2   = (const float*)d_in[39];
  const float* rb2   = (const float*)d_in[40];
  const float* gum   = (const float*)d_in[41];

  float* ws = (float*)d_ws;
  float* x1c  = ws + OFF_X1C;
  float* x2c  = ws + OFF_X2C;
  float* x3c  = ws + OFF_X3C;
  float* x4   = ws + OFF_X4;
  float* emb  = ws + OFF_EMB;
  float* fulls= ws + OFF_FULL;
  float* priB = ws + OFF_PRI;
  float* posB = ws + OFF_POS;
  float* d0tc = ws + OFF_D0T;
  float* dd1c = ws + OFF_DD1;
  float* dd2c = ws + OFF_DD2;
  float* dd3c = ws + OFF_DD3;
  float* w1t  = ws + OFF_W1T;
  float* w2t  = ws + OFF_W2T;
  float* w3t  = ws + OFF_W3T;
  float* w4p  = ws + OFF_W4P;
  int*   cidx = (int*)(ws + OFF_CIDX);
  int*   bars = (int*)(ws + OFF_BARS);
  double* accs= (double*)(ws + OFF_ACC);

  k_init<<<1, 512, 0, stream>>>(bars, accs);

  // encoder in 5 frame-chunks of 208
  for (int fc = 0; fc < 5; ++fc) {
    int fb = fc*CHF;
    k_conv1<<<CHF, 256, 0, stream>>>(obs, ew1, eb1, x1c, fb);
    k_conv2<<<dim3(CHF,2), 256, 0, stream>>>(x1c, ew2, eb2, x2c);
    k_conv3<<<CHF, 256, 0, stream>>>(x2c, ew3, eb3, x3c);
    k_conv4<<<dim3(CHF/16,4), 256, 0, stream>>>(x3c, ew4, eb4, x4, fb);
  }
  k_enclin<<<260, 256, 0, stream>>>(x4, enc_lw, enc_lb, emb);

  ScanArgs sa;
  sa.pre_w = pre_w; sa.pre_b = pre_b;
  sa.wi = gru_wi; sa.wh = gru_wh; sa.bi = gru_bi; sa.bh = gru_bh;
  sa.qw1 = post_w1; sa.qb1 = post_b1; sa.qw2 = post_w2; sa.qb2 = post_b2;
  sa.emb = emb; sa.gum = gum; sa.act = act;
  sa.hbuf = ws + OFF_H; sa.gibuf = ws + OFF_GI; sa.ghbuf = ws + OFF_GH;
  sa.q1buf = ws + OFF_Q1; sa.fulls = fulls; sa.posts = posB;
  sa.curidx = cidx; sa.bars = bars;
  k_scan<<<256, 256, 0, stream>>>(sa);   // 256 blocks <= 256 CUs: co-resident

  k_priors<<<64, 256, 0, stream>>>(fulls, pri_w1, pri_b1, pri_w2, pri_b2, priB);
  k_wtrans<<<12800, 256, 0, stream>>>(dw1, dw2, dw3, dw4, w1t, w2t, w3t, w4p);

  // decoder in 4 sample-chunks of 256
  for (int nc = 0; nc < 4; ++nc) {
    int nb = nc*CHN;
    k_declin<<<32, 256, 0, stream>>>(fulls, dec_lw, dec_lb, d0tc, nb);
    k_ct1<<<100, 256, 0, stream>>>(d0tc, w1t, db1, dd1c);
    k_ct2<<<dim3(169,2), 256, 0, stream>>>(dd1c, w2t, db2, dd2c);
    k_ct3<<<900, 256, 0, stream>>>(dd2c, w3t, db3, dd3c);
    k_ct4loss<<<512, 512, 0, stream>>>(dd3c, w4p, db4, obs, accs + 0, nb);
  }

  k_reward<<<128, 256, 0, stream>>>(fulls, rw1, rb1, rw2, rb2, rew, accs + 1);
  k_kl<<<128, 256, 0, stream>>>(posB, priB, accs + 2);
  k_fin<<<1, 1, 0, stream>>>(accs, (float*)d_out);
}

// Round 10
// 14307.721 us; speedup vs baseline: 1.2259x; 1.2259x over previous
//
#include <hip/hip_runtime.h>
#include <math.h>

#define DI __device__ __forceinline__

// ---------------- dims ----------------
constexpr int TB = 16, TT = 64, NF = 1040, FSD = 1280;
constexpr int CHF = 208;   // encoder frame-chunk (5 chunks)
constexpr int CHN = 256;   // decoder sample-chunk (4 chunks)

// ---------------- ws layout (float offsets), total ~19.9M floats = 79.6 MB ----------------
constexpr size_t OFF_X1C  = 0;
constexpr size_t OFF_X2C  = 6815744;
constexpr size_t OFF_X3C  = 10223616;
constexpr size_t OFF_D0T  = 0;
constexpr size_t OFF_DD1  = 262144;
constexpr size_t OFF_DD2  = 1081344;
constexpr size_t OFF_DD3  = 3850240;
constexpr size_t OFF_X4   = 11927552;
constexpr size_t OFF_W1T  = 11927552;
constexpr size_t OFF_W2T  = 15204352;
constexpr size_t OFF_W3T  = 15409152;
constexpr size_t OFF_W4P  = 15482880;
constexpr size_t OFF_EMB  = 16187392;
constexpr size_t OFF_FULL = 16453632;
constexpr size_t OFF_PRI  = 17764352;
constexpr size_t OFF_POS  = 18812928;
constexpr size_t OFF_ACC  = 19895296;   // 8 doubles, byte off %8==0
constexpr size_t WS_NEED_BYTES = (OFF_ACC + 16) * 4;

// ================= init =================
__global__ void k_init(double* accs) {
  int i = threadIdx.x;
  if (i < 4) accs[i] = 0.0;
}

// ================= encoder conv1: 3x64x64 -> 32x32x32 (chunk of CHF frames) =================
__global__ void __launch_bounds__(256) k_conv1(const float* __restrict__ obs,
    const float* __restrict__ w, const float* __restrict__ b, float* __restrict__ out, int fb) {
  __shared__ float in_s[3*66*66];
  __shared__ float w_s[32*48];
  const int f = blockIdx.x, tid = threadIdx.x;
  const float* src = obs + (size_t)(fb + f)*12288;
  for (int i = tid; i < 3*66*66; i += 256) {
    int c = i/4356, p = i%4356, y = p/66, x = p%66;
    float v = 0.f;
    if (y >= 1 && y <= 64 && x >= 1 && x <= 64) v = src[(c<<12) + ((y-1)<<6) + (x-1)];
    in_s[i] = v;
  }
  for (int i = tid; i < 32*48; i += 256) w_s[i] = w[i];
  __syncthreads();
  for (int pp = 0; pp < 4; ++pp) {
    int pos = tid + pp*256;
    int y = pos >> 5, x = pos & 31;
    float tp[48];
    #pragma unroll
    for (int c = 0; c < 3; ++c)
      #pragma unroll
      for (int ky = 0; ky < 4; ++ky)
        #pragma unroll
        for (int kx = 0; kx < 4; ++kx)
          tp[c*16+ky*4+kx] = in_s[c*4356 + (2*y+ky)*66 + (2*x+kx)];
    for (int o = 0; o < 32; ++o) {
      float acc = b[o];
      #pragma unroll
      for (int t = 0; t < 48; ++t) acc += tp[t]*w_s[o*48+t];
      out[((size_t)f*32 + o)*1024 + pos] = fmaxf(acc, 0.f);
    }
  }
}

// ================= conv2: 32x32x32 -> 64x16x16 (chunk-local) =================
__global__ void __launch_bounds__(256) k_conv2(const float* __restrict__ in,
    const float* __restrict__ w, const float* __restrict__ bias, float* __restrict__ out) {
  __shared__ float in_s[8*34*34];
  __shared__ float w_s[32*128];
  const int f = blockIdx.x, oh = blockIdx.y, tid = threadIdx.x;
  const int y = tid >> 4, x = tid & 15;
  float acc[32];
  #pragma unroll
  for (int o = 0; o < 32; ++o) acc[o] = bias[oh*32 + o];
  for (int cc = 0; cc < 4; ++cc) {
    __syncthreads();
    for (int i = tid; i < 8*34*34; i += 256) {
      int c = i/1156, p = i%1156, yy = p/34, xx = p%34;
      float v = 0.f;
      if (yy >= 1 && yy <= 32 && xx >= 1 && xx <= 32)
        v = in[((size_t)f*32 + cc*8 + c)*1024 + ((yy-1)<<5) + (xx-1)];
      in_s[i] = v;
    }
    for (int i = tid; i < 4096; i += 256) {
      int o = i >> 7, r = i & 127;
      w_s[i] = w[(oh*32+o)*512 + cc*128 + r];
    }
    __syncthreads();
    #pragma unroll
    for (int c = 0; c < 8; ++c) {
      float tp[16];
      #pragma unroll
      for (int ky = 0; ky < 4; ++ky)
        #pragma unroll
        for (int kx = 0; kx < 4; ++kx)
          tp[ky*4+kx] = in_s[c*1156 + (2*y+ky)*34 + (2*x+kx)];
      #pragma unroll
      for (int o = 0; o < 32; ++o) {
        float a2 = acc[o];
        #pragma unroll
        for (int t = 0; t < 16; ++t) a2 += tp[t]*w_s[(o<<7) + (c<<4) + t];
        acc[o] = a2;
      }
    }
  }
  #pragma unroll
  for (int o = 0; o < 32; ++o)
    out[((size_t)f*64 + oh*32 + o)*256 + tid] = fmaxf(acc[o], 0.f);
}

// ================= conv3: 64x16x16 -> 128x8x8 (chunk-local) =================
__global__ void __launch_bounds__(256) k_conv3(const float* __restrict__ in,
    const float* __restrict__ w, const float* __restrict__ bias, float* __restrict__ out) {
  __shared__ float in_s[4*18*18];
  __shared__ float w_s[128*64];
  const int f = blockIdx.x, tid = threadIdx.x;
  const int pos = tid & 63, cog = tid >> 6;
  const int y = pos >> 3, x = pos & 7;
  float acc[32];
  #pragma unroll
  for (int o = 0; o < 32; ++o) acc[o] = bias[cog*32+o];
  for (int cc = 0; cc < 16; ++cc) {
    __syncthreads();
    for (int i = tid; i < 1296; i += 256) {
      int c = i/324, p = i%324, yy = p/18, xx = p%18;
      float v = 0.f;
      if (yy >= 1 && yy <= 16 && xx >= 1 && xx <= 16)
        v = in[((size_t)f*64 + cc*4 + c)*256 + ((yy-1)<<4) + (xx-1)];
      in_s[i] = v;
    }
    for (int i = tid; i < 8192; i += 256) {
      int o = i >> 6, r = i & 63;
      w_s[i] = w[o*1024 + cc*64 + r];
    }
    __syncthreads();
    #pragma unroll
    for (int c = 0; c < 4; ++c) {
      float tp[16];
      #pragma unroll
      for (int ky = 0; ky < 4; ++ky)
        #pragma unroll
        for (int kx = 0; kx < 4; ++kx)
          tp[ky*4+kx] = in_s[c*324 + (2*y+ky)*18 + (2*x+kx)];
      #pragma unroll
      for (int o = 0; o < 32; ++o) {
        float a2 = acc[o];
        #pragma unroll
        for (int t = 0; t < 16; ++t) a2 += tp[t]*w_s[((cog*32+o)<<6) + (c<<4) + t];
        acc[o] = a2;
      }
    }
  }
  #pragma unroll
  for (int o = 0; o < 32; ++o)
    out[((size_t)f*128 + cog*32 + o)*64 + pos] = fmaxf(acc[o], 0.f);
}

// ================= conv4 (GEMM-ish): 128x8x8 -> 256x4x4 =================
__global__ void __launch_bounds__(256) k_conv4(const float* __restrict__ in,
    const float* __restrict__ w, const float* __restrict__ bias, float* __restrict__ out, int fb) {
  __shared__ float a_s[32*256];
  __shared__ float w_s[64*32];
  const int f0 = blockIdx.x * 16, o0 = blockIdx.y * 64, tid = threadIdx.x;
  const int fl = tid >> 4, pos = tid & 15;
  float acc[64];
  #pragma unroll
  for (int o = 0; o < 64; ++o) acc[o] = 0.f;
  for (int K0 = 0; K0 < 2048; K0 += 32) {
    __syncthreads();
    for (int i = tid; i < 8192; i += 256) {
      int kk = i >> 8, row = i & 255;
      int K = K0 + kk, ci = K >> 4, tap = K & 15;
      int ff = f0 + (row >> 4), pp = row & 15;
      int yy = ((pp >> 2) << 1) + (tap >> 2) - 1;
      int xx = ((pp & 3) << 1) + (tap & 3) - 1;
      float v = 0.f;
      if (yy >= 0 && yy < 8 && xx >= 0 && xx < 8)
        v = in[((size_t)ff*128 + ci)*64 + yy*8 + xx];
      a_s[kk*256 + row] = v;
    }
    for (int i = tid; i < 2048; i += 256) {
      int o = i >> 5, kk = i & 31;
      w_s[i] = w[(o0 + o)*2048 + K0 + kk];
    }
    __syncthreads();
    #pragma unroll
    for (int kk = 0; kk < 32; ++kk) {
      float av = a_s[kk*256 + tid];
      #pragma unroll
      for (int o = 0; o < 64; ++o) acc[o] += av * w_s[o*32 + kk];
    }
  }
  for (int o = 0; o < 64; ++o)
    out[(((size_t)(fb + f0 + fl))*256 + o0+o)*16 + pos] = fmaxf(acc[o] + bias[o0+o], 0.f);
}

// ================= encoder linear: 1040x4096 @ 4096x256 =================
__global__ void __launch_bounds__(256) k_enclin(const float* __restrict__ x4,
    const float* __restrict__ w, const float* __restrict__ b, float* __restrict__ emb) {
  __shared__ float a_s[4*1024];
  const int f0 = blockIdx.x*4, tid = threadIdx.x;
  float acc[4] = {0.f,0.f,0.f,0.f};
  for (int K0 = 0; K0 < 4096; K0 += 1024) {
    __syncthreads();
    for (int i = tid; i < 4096; i += 256) {
      int r = i >> 10, k = i & 1023;
      a_s[i] = x4[((size_t)(f0+r))*4096 + K0 + k];
    }
    __syncthreads();
    for (int k = 0; k < 1024; ++k) {
      float wv = w[(K0+k)*256 + tid];
      #pragma unroll
      for (int r = 0; r < 4; ++r) acc[r] += a_s[(r<<10) + k] * wv;
    }
  }
  #pragma unroll
  for (int r = 0; r < 4; ++r) emb[((size_t)(f0+r))*256 + tid] = acc[r] + b[tid];
}

// ================= decoder weight transforms =================
__global__ void k_wtrans(const float* __restrict__ dw1, const float* __restrict__ dw2,
                         const float* __restrict__ dw3, const float* __restrict__ dw4,
                         float* __restrict__ w1t, float* __restrict__ w2t,
                         float* __restrict__ w3t, float* __restrict__ w4p) {
  int i = blockIdx.x*256 + threadIdx.x;
  if (i < 1024*3200) {
    int k = i / 3200, c = i % 3200;
    int o = c / 25, r = c % 25, y = r / 5, x = r % 5;
    w1t[i] = dw1[(o*1024 + k)*25 + (4-y)*5 + (4-x)];
  }
  if (i < 25*128*64) {
    int tap = i / 8192, r = i % 8192, ii = r >> 6, o = r & 63;
    w2t[i] = dw2[(o*128 + ii)*25 + tap];
  }
  if (i < 36*64*32) {
    int tap = i / 2048, r = i % 2048, ii = r >> 5, o = r & 31;
    w3t[i] = dw3[(o*64 + ii)*36 + tap];
  }
  if (i < 4*9*96) {
    int par = i / 864, r = i % 864, d9 = r / 96, q = r % 96, ii = q/3, o = q%3;
    int py = par >> 1, px = par & 1, d2 = d9 / 3, d = d9 % 3;
    int ky = 5 - py - 2*d2, kx = 5 - px - 2*d;
    w4p[i] = dw4[(o*32 + ii)*36 + ky*6 + kx];
  }
}

// ================= RSSM scan v2: one block per chain, LDS-only sync =================
struct Scan2Args {
  const float *pre_w, *pre_b, *wi, *wh, *bi, *bh, *qw1, *qb1, *qw2, *qb2, *emb, *gum;
  const int* act;
  float *fulls, *posts;
};

__global__ void __launch_bounds__(1024) k_scan2(Scan2Args a) {
  const int tid = threadIdx.x;
  const int chain = blockIdx.x;
  __shared__ float xin_s[256], h_s[256], e_s[256], q1_s[256];
  __shared__ float gi_s[768], gh_s[768];
  __shared__ float post_s[1024];
  __shared__ float red_s[512];
  __shared__ int cidx_s[32];
  if (tid < 256) h_s[tid] = 0.f;
  __syncthreads();
  for (int t = 0; t < TT; ++t) {
    const int row = chain*TT + t;
    // ---- xin (threads 256..511) + e load (threads 0..255) ----
    if (tid < 256) {
      e_s[tid] = a.emb[((size_t)chain*65 + t + 1)*256 + tid];
    } else if (tid < 512) {
      int i = tid - 256;
      float v = a.pre_b[i];
      int act = a.act[chain*TT + t];
      v += a.pre_w[(size_t)(1024 + act)*256 + i];
      if (t > 0) {
        #pragma unroll
        for (int c = 0; c < 32; ++c)
          v += a.pre_w[(size_t)(c*32 + cidx_s[c])*256 + i];
      }
      xin_s[i] = fmaxf(v, 0.f);
    }
    __syncthreads();
    // ---- gi (768 cols) + gh (768 cols): 1.5 passes over 1024 threads ----
    if (tid < 768) {
      float p = 0.f;
      #pragma unroll 8
      for (int k = 0; k < 256; ++k) p += xin_s[k] * a.wi[(size_t)k*768 + tid];
      gi_s[tid] = p + a.bi[tid];
    } else {
      int c2 = tid - 768;
      float p = 0.f;
      #pragma unroll 8
      for (int k = 0; k < 256; ++k) p += h_s[k] * a.wh[(size_t)k*768 + c2];
      gh_s[c2] = p + a.bh[c2];
    }
    if (tid < 512) {
      int c2 = 256 + tid;
      float p = 0.f;
      #pragma unroll 8
      for (int k = 0; k < 256; ++k) p += h_s[k] * a.wh[(size_t)k*768 + c2];
      gh_s[c2] = p + a.bh[c2];
    }
    __syncthreads();
    // ---- gates -> h ----
    if (tid < 256) {
      float rr = 1.f/(1.f+expf(-(gi_s[tid]      + gh_s[tid])));
      float zz = 1.f/(1.f+expf(-(gi_s[256+tid]  + gh_s[256+tid])));
      float nn = tanhf(gi_s[512+tid] + rr*gh_s[512+tid]);
      float hn = (1.f - zz)*nn + zz*h_s[tid];
      h_s[tid] = hn;
      a.fulls[(size_t)row*FSD + tid] = hn;
    }
    __syncthreads();
    // ---- q1: 512 threads, 2-way K split ----
    if (tid < 512) {
      int col = tid & 255, half = tid >> 8;
      int k0 = half << 8;
      float p = 0.f;
      #pragma unroll 8
      for (int k2 = 0; k2 < 256; ++k2) {
        int kk = k0 + k2;
        float v = (kk < 256) ? h_s[kk] : e_s[kk-256];
        p += v * a.qw1[(size_t)kk*256 + col];
      }
      red_s[tid] = p;
    }
    __syncthreads();
    if (tid < 256) q1_s[tid] = fmaxf(red_s[tid] + red_s[256+tid] + a.qb1[tid], 0.f);
    __syncthreads();
    // ---- post: one col per thread ----
    {
      float p = 0.f;
      #pragma unroll 8
      for (int k = 0; k < 256; ++k) p += q1_s[k] * a.qw2[(size_t)k*1024 + tid];
      p += a.qb2[tid];
      post_s[tid] = p;
      a.posts[(size_t)row*1024 + tid] = p;
    }
    __syncthreads();
    // ---- argmax (32 lanes per category, first-occurrence) + one-hot stoch ----
    {
      int cat = tid >> 5, k = tid & 31;
      float v = post_s[cat*32 + k] + a.gum[(((size_t)t*16 + chain)*32 + cat)*32 + k];
      int bidx = k;
      #pragma unroll
      for (int off = 16; off > 0; off >>= 1) {
        float ov = __shfl_down(v, off, 32);
        int oi = __shfl_down(bidx, off, 32);
        if (ov > v || (ov == v && oi < bidx)) { v = ov; bidx = oi; }  // (max, min-index): first-occurrence argmax
      }
      int best = __shfl(bidx, 0, 32);
      if (k == 0) cidx_s[cat] = best;
      a.fulls[(size_t)row*FSD + 256 + tid] = (k == best) ? 1.f : 0.f;
    }
    __syncthreads();   // cidx_s / h_s / e_s stable before next iteration
  }
}

// ================= priors (batched, post-scan) =================
__global__ void __launch_bounds__(256) k_priors(const float* __restrict__ fulls,
    const float* __restrict__ w1, const float* __restrict__ b1,
    const float* __restrict__ w2, const float* __restrict__ b2, float* __restrict__ priors) {
  __shared__ float h_s[16*256];
  __shared__ float p1_s[16*256];
  const int r0 = blockIdx.x*16, tid = threadIdx.x;
  for (int i = tid; i < 4096; i += 256) {
    int r = i >> 8, k = i & 255;
    h_s[i] = fulls[((size_t)(r0+r))*FSD + k];
  }
  __syncthreads();
  float acc[16];
  #pragma unroll
  for (int r = 0; r < 16; ++r) acc[r] = b1[tid];
  for (int k = 0; k < 256; ++k) {
    float wv = w1[k*256 + tid];
    #pragma unroll
    for (int r = 0; r < 16; ++r) acc[r] += h_s[(r<<8)+k]*wv;
  }
  #pragma unroll
  for (int r = 0; r < 16; ++r) p1_s[(r<<8)+tid] = fmaxf(acc[r], 0.f);
  __syncthreads();
  float a2[16][4];
  #pragma unroll
  for (int r = 0; r < 16; ++r)
    #pragma unroll
    for (int q = 0; q < 4; ++q) a2[r][q] = b2[q*256 + tid];
  for (int k = 0; k < 256; ++k) {
    float w0 = w2[k*1024 + tid], wv1 = w2[k*1024 + 256 + tid];
    float wv2 = w2[k*1024 + 512 + tid], wv3 = w2[k*1024 + 768 + tid];
    #pragma unroll
    for (int r = 0; r < 16; ++r) {
      float pv = p1_s[(r<<8)+k];
      a2[r][0] += pv*w0; a2[r][1] += pv*wv1; a2[r][2] += pv*wv2; a2[r][3] += pv*wv3;
    }
  }
  for (int r = 0; r < 16; ++r)
    #pragma unroll
    for (int q = 0; q < 4; ++q)
      priors[((size_t)(r0+r))*1024 + q*256 + tid] = a2[r][q];
}

// ================= decoder linear (chunk) =================
__global__ void __launch_bounds__(256) k_declin(const float* __restrict__ fulls,
    const float* __restrict__ w, const float* __restrict__ b, float* __restrict__ d0t, int nb) {
  __shared__ float f_s[32*257];
  __shared__ float w_s[32*32];
  const int k0 = blockIdx.x*32, tid = threadIdx.x;
  float acc[32];
  #pragma unroll
  for (int kt = 0; kt < 32; ++kt) acc[kt] = 0.f;
  for (int K0 = 0; K0 < 1280; K0 += 32) {
    __syncthreads();
    {
      const float4* src = (const float4*)(fulls + ((size_t)(nb+tid))*FSD + K0);
      #pragma unroll
      for (int q = 0; q < 8; ++q) {
        float4 v = src[q];
        f_s[(q*4+0)*257 + tid] = v.x;
        f_s[(q*4+1)*257 + tid] = v.y;
        f_s[(q*4+2)*257 + tid] = v.z;
        f_s[(q*4+3)*257 + tid] = v.w;
      }
    }
    for (int i = tid; i < 1024; i += 256) {
      int kk = i >> 5, kt = i & 31;
      w_s[i] = w[(size_t)(K0+kk)*1024 + k0 + kt];
    }
    __syncthreads();
    #pragma unroll
    for (int kk = 0; kk < 32; ++kk) {
      float hv = f_s[kk*257 + tid];
      #pragma unroll
      for (int kt = 0; kt < 32; ++kt) acc[kt] += hv * w_s[kk*32 + kt];
    }
  }
  for (int kt = 0; kt < 32; ++kt) d0t[((size_t)(k0+kt))*CHN + tid] = acc[kt] + b[k0+kt];
}

// ================= ct1: GEMM 1024K x 3200 cols (chunk) =================
__global__ void __launch_bounds__(256) k_ct1(const float* __restrict__ d0t,
    const float* __restrict__ w1t, const float* __restrict__ db1, float* __restrict__ dd1) {
  __shared__ float w_s[32*32];
  const int c0 = blockIdx.x*32, tid = threadIdx.x;
  float acc[32];
  #pragma unroll
  for (int ct = 0; ct < 32; ++ct) acc[ct] = 0.f;
  for (int K0 = 0; K0 < 1024; K0 += 32) {
    __syncthreads();
    for (int i = tid; i < 1024; i += 256) {
      int kk = i >> 5, ct = i & 31;
      w_s[i] = w1t[(size_t)(K0+kk)*3200 + c0 + ct];
    }
    __syncthreads();
    #pragma unroll
    for (int kk = 0; kk < 32; ++kk) {
      float av = d0t[((size_t)(K0+kk))*CHN + tid];
      #pragma unroll
      for (int ct = 0; ct < 32; ++ct) acc[ct] += av * w_s[kk*32 + ct];
    }
  }
  #pragma unroll
  for (int ct = 0; ct < 32; ++ct)
    dd1[((size_t)(c0+ct))*CHN + tid] = fmaxf(acc[ct] + db1[(c0+ct)/25], 0.f);
}

// ================= ct2: 128x5x5 -> 64x13x13 (chunk) =================
__global__ void __launch_bounds__(256) k_ct2(const float* __restrict__ dd1,
    const float* __restrict__ w2t, const float* __restrict__ db2, float* __restrict__ dd2) {
  __shared__ float w_s[128*32];
  const int pos = blockIdx.x, og = blockIdx.y, tid = threadIdx.x;
  const int y = pos/13, x = pos%13;
  const int nl2 = (tid & 127)*2, oh = tid >> 7;
  float acc[16][2];
  #pragma unroll
  for (int o = 0; o < 16; ++o) { acc[o][0] = 0.f; acc[o][1] = 0.f; }
  for (int ky = 0; ky < 5; ++ky) {
    int ty = y + ky - 4;
    if (ty & 1) continue;
    int iy = ty >> 1;
    if (iy < 0 || iy >= 5) continue;
    for (int kx = 0; kx < 5; ++kx) {
      int tx = x + kx - 4;
      if (tx & 1) continue;
      int ix = tx >> 1;
      if (ix < 0 || ix >= 5) continue;
      int tap = ky*5 + kx;
      __syncthreads();
      for (int i = tid; i < 4096; i += 256)
        w_s[i] = w2t[(size_t)tap*8192 + (i >> 5)*64 + og*32 + (i & 31)];
      __syncthreads();
      #pragma unroll 4
      for (int i = 0; i < 128; ++i) {
        float2 v = *(const float2*)(dd1 + ((size_t)(i*25 + iy*5 + ix))*CHN + nl2);
        #pragma unroll
        for (int o = 0; o < 16; ++o) {
          float wv = w_s[i*32 + oh*16 + o];
          acc[o][0] += v.x*wv; acc[o][1] += v.y*wv;
        }
      }
    }
  }
  for (int o = 0; o < 16; ++o) {
    int oo = og*32 + oh*16 + o;
    float bb = db2[oo];
    float2 r; r.x = fmaxf(acc[o][0]+bb, 0.f); r.y = fmaxf(acc[o][1]+bb, 0.f);
    *(float2*)(dd2 + ((size_t)(oo*169 + pos))*CHN + nl2) = r;
  }
}

// ================= ct3: 64x13x13 -> 32x30x30 (chunk) =================
__global__ void __launch_bounds__(256) k_ct3(const float* __restrict__ dd2,
    const float* __restrict__ w3t, const float* __restrict__ db3, float* __restrict__ dd3) {
  __shared__ float w_s[64*32];
  const int pos = blockIdx.x, tid = threadIdx.x;
  const int y = pos/30, x = pos%30;
  const int nl2 = (tid & 127)*2, oh = tid >> 7;
  float acc[16][2];
  #pragma unroll
  for (int o = 0; o < 16; ++o) { acc[o][0] = 0.f; acc[o][1] = 0.f; }
  for (int ky = 0; ky < 6; ++ky) {
    int ty = y + ky - 5;
    if (ty & 1) continue;
    int iy = ty >> 1;
    if (iy < 0 || iy >= 13) continue;
    for (int kx = 0; kx < 6; ++kx) {
      int tx = x + kx - 5;
      if (tx & 1) continue;
      int ix = tx >> 1;
      if (ix < 0 || ix >= 13) continue;
      int tap = ky*6 + kx;
      __syncthreads();
      for (int i = tid; i < 2048; i += 256) w_s[i] = w3t[(size_t)tap*2048 + i];
      __syncthreads();
      #pragma unroll 2
      for (int i = 0; i < 64; ++i) {
        float2 v = *(const float2*)(dd2 + ((size_t)(i*169 + iy*13 + ix))*CHN + nl2);
        #pragma unroll
        for (int o = 0; o < 16; ++o) {
          float wv = w_s[i*32 + oh*16 + o];
          acc[o][0] += v.x*wv; acc[o][1] += v.y*wv;
        }
      }
    }
  }
  for (int o = 0; o < 16; ++o) {
    int oo = oh*16 + o;
    float bb = db3[oo];
    float2 r; r.x = fmaxf(acc[o][0]+bb, 0.f); r.y = fmaxf(acc[o][1]+bb, 0.f);
    *(float2*)(dd3 + ((size_t)(oo*900 + pos))*CHN + nl2) = r;
  }
}

// ====== ct4 fused with recon MSE; parity-decomposed; chunk n ======
__global__ void __launch_bounds__(512) k_ct4loss(const float* __restrict__ dd3,
    const float* __restrict__ w4p, const float* __restrict__ db4,
    const float* __restrict__ obs, double* __restrict__ accRec, int nb) {
  __shared__ float in_s[16*10*6*16];
  __shared__ float redf[8];
  const int tid = threadIdx.x, bx = blockIdx.x;
  const int nbt = bx & 15, xt = (bx >> 4) & 7, yt = bx >> 7;
  const int n0 = nbt*16, Y0 = yt*8, X0 = xt*4;
  const int nl = tid & 15, ppos = tid >> 4;
  const int yl = ppos >> 2, xl = ppos & 3;
  float acc[4][3];
  #pragma unroll
  for (int p = 0; p < 4; ++p) { acc[p][0]=db4[0]; acc[p][1]=db4[1]; acc[p][2]=db4[2]; }
  for (int ch = 0; ch < 2; ++ch) {
    __syncthreads();
    for (int i = tid; i < 15360; i += 512) {
      int n2 = i & 15, r = i >> 4;
      int ix = r % 6, r2 = r / 6, iy = r2 % 10, ii = r2 / 10;
      int gy = Y0 - 2 + iy, gx = X0 - 2 + ix;
      float v = 0.f;
      if (gy >= 0 && gy < 30 && gx >= 0 && gx < 30)
        v = dd3[((size_t)((ch*16 + ii)*900 + gy*30 + gx))*CHN + n0 + n2];
      in_s[i] = v;
    }
    __syncthreads();
    #pragma unroll
    for (int par = 0; par < 4; ++par) {
      #pragma unroll
      for (int d2 = 0; d2 < 3; ++d2) {
        int iy = yl + 2 - d2;
        #pragma unroll
        for (int d = 0; d < 3; ++d) {
          int ix = xl + 2 - d;
          const float* wp = w4p + (par*9 + d2*3 + d)*96 + ch*48;
          #pragma unroll 4
          for (int ii = 0; ii < 16; ++ii) {
            float v = in_s[((ii*10 + iy)*6 + ix)*16 + nl];
            acc[par][0] += v*wp[ii*3+0];
            acc[par][1] += v*wp[ii*3+1];
            acc[par][2] += v*wp[ii*3+2];
          }
        }
      }
    }
  }
  const int n = nb + n0 + nl, b = n >> 6, t = n & 63;
  float lsum = 0.f;
  #pragma unroll
  for (int par = 0; par < 4; ++par) {
    int py = par >> 1, px = par & 1;
    int yy = 2*(Y0 + yl) + py, xx = 2*(X0 + xl) + px;
    const float* ob = obs + (size_t)((b*65 + t + 1)*3)*4096 + yy*64 + xx;
    float d0v = acc[par][0] - ob[0];
    float d1v = acc[par][1] - ob[4096];
    float d2v = acc[par][2] - ob[8192];
    lsum += d0v*d0v + d1v*d1v + d2v*d2v;
  }
  #pragma unroll
  for (int off = 32; off > 0; off >>= 1) lsum += __shfl_down(lsum, off);
  if ((tid & 63) == 0) redf[tid >> 6] = lsum;
  __syncthreads();
  if (tid == 0) {
    float s = 0.f;
    for (int i = 0; i < 8; ++i) s += redf[i];
    atomicAdd(accRec, (double)s);
  }
}

// ================= reward head + MSE =================
__global__ void __launch_bounds__(256) k_reward(const float* __restrict__ fulls,
    const float* __restrict__ w1, const float* __restrict__ b1,
    const float* __restrict__ w2, const float* __restrict__ b2,
    const float* __restrict__ rew, double* __restrict__ accR) {
  __shared__ float f_s[8*1280];
  __shared__ float h_s[8*256];
  const int r0 = blockIdx.x*8, tid = threadIdx.x;
  for (int i = tid; i < 8*1280; i += 256) f_s[i] = fulls[(size_t)r0*FSD + i];
  __syncthreads();
  float acc[8];
  #pragma unroll
  for (int r = 0; r < 8; ++r) acc[r] = b1[tid];
  for (int k = 0; k < 1280; ++k) {
    float wv = w1[(size_t)k*256 + tid];
    #pragma unroll
    for (int r = 0; r < 8; ++r) acc[r] += f_s[r*1280 + k] * wv;
  }
  #pragma unroll
  for (int r = 0; r < 8; ++r) h_s[(r<<8) + tid] = fmaxf(acc[r], 0.f);
  __syncthreads();
  int r = tid >> 5, l = tid & 31;
  float p = 0.f;
  for (int j = l; j < 256; j += 32) p += h_s[(r<<8) + j] * w2[j];
  #pragma unroll
  for (int off = 16; off > 0; off >>= 1) p += __shfl_down(p, off, 32);
  if (l == 0) {
    float d = p + b2[0] - rew[r0 + r];
    atomicAdd(accR, (double)(d*d));
  }
}

// ================= KL =================
__global__ void __launch_bounds__(256) k_kl(const float* __restrict__ posts,
    const float* __restrict__ priors, double* __restrict__ accK) {
  const int u = blockIdx.x*256 + threadIdx.x;
  const float* po = posts  + (size_t)(u >> 5)*1024 + (u & 31)*32;
  const float* pr = priors + (size_t)(u >> 5)*1024 + (u & 31)*32;
  float pv[32], qv[32];
  float m1 = -1e30f, m2 = -1e30f;
  #pragma unroll
  for (int k = 0; k < 32; ++k) {
    pv[k] = po[k]; m1 = fmaxf(m1, pv[k]);
    qv[k] = pr[k]; m2 = fmaxf(m2, qv[k]);
  }
  float s1 = 0.f, s2 = 0.f;
  #pragma unroll
  for (int k = 0; k < 32; ++k) {
    pv[k] = expf(pv[k]-m1); s1 += pv[k];
    qv[k] = expf(qv[k]-m2); s2 += qv[k];
  }
  float i1 = 1.f/s1, i2 = 1.f/s2;
  float kl = 0.f;
  #pragma unroll
  for (int k = 0; k < 32; ++k) {
    float pp = pv[k]*i1 + 1e-8f;
    float qq = qv[k]*i2 + 1e-8f;
    kl += pp * (logf(pp) - logf(qq));
  }
  #pragma unroll
  for (int off = 32; off > 0; off >>= 1) kl += __shfl_down(kl, off);
  __shared__ float red[4];
  if ((threadIdx.x & 63) == 0) red[threadIdx.x >> 6] = kl;
  __syncthreads();
  if (threadIdx.x == 0) atomicAdd(accK, (double)(red[0]+red[1]+red[2]+red[3]));
}

// ================= finalize =================
__global__ void k_fin(const double* __restrict__ accs, float* __restrict__ out) {
  out[0] = (float)(accs[0]/12582912.0 + accs[1]/1024.0 + accs[2]/32768.0);
}

// ================= launcher =================
extern "C" void kernel_launch(void* const* d_in, const int* in_sizes, int n_in,
                              void* d_out, int out_size, void* d_ws, size_t ws_size,
                              hipStream_t stream) {
  (void)in_sizes; (void)n_in; (void)out_size;
  if (ws_size < WS_NEED_BYTES) return;
  const float* obs   = (const float*)d_in[0];
  const int*   act   = (const int*)  d_in[1];
  const float* rew   = (const float*)d_in[2];
  const float* ew1   = (const float*)d_in[3];
  const float* eb1   = (const float*)d_in[4];
  const float* ew2   = (const float*)d_in[5];
  const float* eb2   = (const float*)d_in[6];
  const float* ew3   = (const float*)d_in[7];
  const float* eb3   = (const float*)d_in[8];
  const float* ew4   = (const float*)d_in[9];
  const float* eb4   = (const float*)d_in[10];
  const float* enc_lw= (const float*)d_in[11];
  const float* enc_lb= (const float*)d_in[12];
  const float* pre_w = (const float*)d_in[13];
  const float* pre_b = (const float*)d_in[14];
  const float* gru_wi= (const float*)d_in[15];
  const float* gru_wh= (const float*)d_in[16];
  const float* gru_bi= (const float*)d_in[17];
  const float* gru_bh= (const float*)d_in[18];
  const float* pri_w1= (const float*)d_in[19];
  const float* pri_b1= (const float*)d_in[20];
  const float* pri_w2= (const float*)d_in[21];
  const float* pri_b2= (const float*)d_in[22];
  const float* post_w1=(const float*)d_in[23];
  const float* post_b1=(const float*)d_in[24];
  const float* post_w2=(const float*)d_in[25];
  const float* post_b2=(const float*)d_in[26];
  const float* dec_lw= (const float*)d_in[27];
  const float* dec_lb= (const float*)d_in[28];
  const float* dw1   = (const float*)d_in[29];
  const float* db1   = (const float*)d_in[30];
  const float* dw2   = (const float*)d_in[31];
  const float* db2   = (const float*)d_in[32];
  const float* dw3   = (const float*)d_in[33];
  const float* db3   = (const float*)d_in[34];
  const float* dw4   = (const float*)d_in[35];
  const float* db4   = (const float*)d_in[36];
  const float* rw1   = (const float*)d_in[37];
  const float* rb1   = (const float*)d_in[38];
  const float* rw2   = (const float*)d_in[39];
  const float* rb2   = (const float*)d_in[40];
  const float* gum   = (const float*)d_in[41];

  float* ws = (float*)d_ws;
  float* x1c  = ws + OFF_X1C;
  float* x2c  = ws + OFF_X2C;
  float* x3c  = ws + OFF_X3C;
  float* x4   = ws + OFF_X4;
  float* emb  = ws + OFF_EMB;
  float* fulls= ws + OFF_FULL;
  float* priB = ws + OFF_PRI;
  float* posB = ws + OFF_POS;
  float* d0tc = ws + OFF_D0T;
  float* dd1c = ws + OFF_DD1;
  float* dd2c = ws + OFF_DD2;
  float* dd3c = ws + OFF_DD3;
  float* w1t  = ws + OFF_W1T;
  float* w2t  = ws + OFF_W2T;
  float* w3t  = ws + OFF_W3T;
  float* w4p  = ws + OFF_W4P;
  double* accs= (double*)(ws + OFF_ACC);

  k_init<<<1, 64, 0, stream>>>(accs);

  for (int fc = 0; fc < 5; ++fc) {
    int fb = fc*CHF;
    k_conv1<<<CHF, 256, 0, stream>>>(obs, ew1, eb1, x1c, fb);
    k_conv2<<<dim3(CHF,2), 256, 0, stream>>>(x1c, ew2, eb2, x2c);
    k_conv3<<<CHF, 256, 0, stream>>>(x2c, ew3, eb3, x3c);
    k_conv4<<<dim3(CHF/16,4), 256, 0, stream>>>(x3c, ew4, eb4, x4, fb);
  }
  k_enclin<<<260, 256, 0, stream>>>(x4, enc_lw, enc_lb, emb);

  Scan2Args sa;
  sa.pre_w = pre_w; sa.pre_b = pre_b;
  sa.wi = gru_wi; sa.wh = gru_wh; sa.bi = gru_bi; sa.bh = gru_bh;
  sa.qw1 = post_w1; sa.qb1 = post_b1; sa.qw2 = post_w2; sa.qb2 = post_b2;
  sa.emb = emb; sa.gum = gum; sa.act = act;
  sa.fulls = fulls; sa.posts = posB;
  k_scan2<<<16, 1024, 0, stream>>>(sa);

  k_priors<<<64, 256, 0, stream>>>(fulls, pri_w1, pri_b1, pri_w2, pri_b2, priB);
  k_wtrans<<<12800, 256, 0, stream>>>(dw1, dw2, dw3, dw4, w1t, w2t, w3t, w4p);

  for (int nc = 0; nc < 4; ++nc) {
    int nb = nc*CHN;
    k_declin<<<32, 256, 0, stream>>>(fulls, dec_lw, dec_lb, d0tc, nb);
    k_ct1<<<100, 256, 0, stream>>>(d0tc, w1t, db1, dd1c);
    k_ct2<<<dim3(169,2), 256, 0, stream>>>(dd1c, w2t, db2, dd2c);
    k_ct3<<<900, 256, 0, stream>>>(dd2c, w3t, db3, dd3c);
    k_ct4loss<<<512, 512, 0, stream>>>(dd3c, w4p, db4, obs, accs + 0, nb);
  }

  k_reward<<<128, 256, 0, stream>>>(fulls, rw1, rb1, rw2, rb2, rew, accs + 1);
  k_kl<<<128, 256, 0, stream>>>(posB, priB, accs + 2);
  k_fin<<<1, 1, 0, stream>>>(accs, (float*)d_out);
}